// Round 1
// baseline (773.736 us; speedup 1.0000x reference)
//
#include <hip/hip_runtime.h>

#define IN_C 256
#define HIDC 32
#define OUTC 16

// ---------------- edge index loader (handles int32 or int64 storage) -------
// If the buffer actually holds int64 (little-endian), element i's low word is
// at 32-bit index 2*i (values < 2^31 so the low word is the value).
__device__ __forceinline__ int edge_at(const int* __restrict__ ei, long long idx, int is64) {
    return is64 ? ei[idx << 1] : ei[idx];
}

// Detect int64 vs int32 storage: sample odd 32-bit words; all-zero => int64.
__global__ void k_detect(const int* __restrict__ ei, int* __restrict__ flag) {
    __shared__ int nz;
    if (threadIdx.x == 0) nz = 0;
    __syncthreads();
    if (ei[2 * threadIdx.x + 1] != 0) atomicOr(&nz, 1);
    __syncthreads();
    if (threadIdx.x == 0) *flag = (nz == 0) ? 1 : 0;
}

// ---------------- degree histogram over dst --------------------------------
__global__ void k_deg(const int* __restrict__ ei, long long E,
                      const int* __restrict__ flag, float* __restrict__ deg) {
    int is64 = *flag;
    long long stride = (long long)gridDim.x * blockDim.x;
    for (long long i = (long long)blockIdx.x * blockDim.x + threadIdx.x; i < E; i += stride)
        atomicAdd(&deg[edge_at(ei, E + i, is64)], 1.0f);
}

// dinv = rsqrt(deg + 1)   (+1 = self-loop), in place
__global__ void k_dinv(float* __restrict__ deg, int n) {
    int i = blockIdx.x * blockDim.x + threadIdx.x;
    if (i < n) deg[i] = rsqrtf(deg[i] + 1.0f);
}

// ---------------- gemm1: h1 = x @ W1  [n,256]x[256,32] ---------------------
// thread-per-node; x staged via LDS in k-chunks of 32 (coalesced global loads,
// conflict-limited LDS reads via stride-40 padding); W1 read wave-uniformly
// (scalar loads -> v_fmac with SGPR operand).
#define G1_KC 32
__global__ __launch_bounds__(256) void k_gemm1(const float* __restrict__ x,
                                               const float* __restrict__ W1,
                                               float* __restrict__ h1, int n) {
    __shared__ float xs[256][40];  // 40 KiB; stride 40 => 16B-aligned rows, 4-way max conflict
    const int t = threadIdx.x;
    const int node = blockIdx.x * 256 + t;
    float acc[HIDC];
#pragma unroll
    for (int o = 0; o < HIDC; ++o) acc[o] = 0.f;

    for (int k0 = 0; k0 < IN_C; k0 += G1_KC) {
        // stage x[block_nodes, k0:k0+32]: 256 rows x 128B, coalesced
#pragma unroll
        for (int it = 0; it < 8; ++it) {
            int i = it * 256 + t;
            int row = i >> 3;       // 8 float4 per row-chunk
            int c4 = i & 7;
            int gnode = blockIdx.x * 256 + row;
            float4 v = make_float4(0.f, 0.f, 0.f, 0.f);
            if (gnode < n)
                v = *(const float4*)(x + (long long)gnode * IN_C + k0 + c4 * 4);
            *(float4*)&xs[row][c4 * 4] = v;
        }
        __syncthreads();
        float xr[G1_KC];
#pragma unroll
        for (int j = 0; j < 8; ++j) {
            float4 v = *(const float4*)&xs[t][j * 4];
            xr[j * 4 + 0] = v.x; xr[j * 4 + 1] = v.y;
            xr[j * 4 + 2] = v.z; xr[j * 4 + 3] = v.w;
        }
#pragma unroll
        for (int kk = 0; kk < G1_KC; ++kk) {
            const float* __restrict__ wrow = W1 + (long long)(k0 + kk) * HIDC;
#pragma unroll
            for (int o = 0; o < HIDC; ++o)
                acc[o] = fmaf(xr[kk], wrow[o], acc[o]);  // wrow uniform -> s_load
        }
        __syncthreads();
    }
    if (node < n) {
#pragma unroll
        for (int j = 0; j < 8; ++j)
            *(float4*)(h1 + (long long)node * HIDC + j * 4) =
                make_float4(acc[j * 4], acc[j * 4 + 1], acc[j * 4 + 2], acc[j * 4 + 3]);
    }
}

// ---------------- layer-1 edge aggregation (atomic scatter) ----------------
// half-wave (32 lanes) per edge: gather contiguous 128B h1[src] row, scale,
// atomicAdd 128B into agg[dst].
#define CH1 1024
__global__ __launch_bounds__(256) void k_agg1(const int* __restrict__ ei, long long E,
                                              const int* __restrict__ flag,
                                              const float* __restrict__ dinv,
                                              const float* __restrict__ h1,
                                              float* __restrict__ agg) {
    int is64 = *flag;
    int lane = threadIdx.x & 63;
    int wv = threadIdx.x >> 6;
    int ch = lane & 31;
    int half = lane >> 5;
    long long base = (long long)blockIdx.x * CH1;
    long long end = base + CH1; if (end > E) end = E;
    for (long long e = base + wv * 2 + half; e < end; e += 8) {
        int s = edge_at(ei, e, is64);
        int d = edge_at(ei, E + e, is64);
        float nrm = dinv[s] * dinv[d];
        float v = h1[(long long)s * HIDC + ch] * nrm;
        atomicAdd(&agg[(long long)d * HIDC + ch], v);
    }
}

// fin1: h1 <- relu(agg + h1*dinv^2 + b1)
__global__ void k_fin1(float* __restrict__ h1, const float* __restrict__ agg,
                       const float* __restrict__ dinv, const float* __restrict__ b1, int n) {
    long long i = (long long)blockIdx.x * blockDim.x + threadIdx.x;
    if (i >= (long long)n * HIDC) return;
    int node = (int)(i >> 5), c = (int)(i & 31);
    float di = dinv[node];
    float v = agg[i] + h1[i] * di * di + b1[c];
    h1[i] = v > 0.f ? v : 0.f;
}

// ---------------- gemm2: h2 = h1r @ W2  [n,32]x[32,16] ---------------------
__global__ __launch_bounds__(256) void k_gemm2(const float* __restrict__ h1,
                                               const float* __restrict__ W2,
                                               float* __restrict__ h2, int n) {
    int node = blockIdx.x * 256 + threadIdx.x;
    if (node >= n) return;
    float xr[HIDC];
#pragma unroll
    for (int j = 0; j < 8; ++j) {
        float4 v = *(const float4*)(h1 + (long long)node * HIDC + j * 4);
        xr[j * 4 + 0] = v.x; xr[j * 4 + 1] = v.y;
        xr[j * 4 + 2] = v.z; xr[j * 4 + 3] = v.w;
    }
    float acc[OUTC];
#pragma unroll
    for (int o = 0; o < OUTC; ++o) acc[o] = 0.f;
#pragma unroll
    for (int kk = 0; kk < HIDC; ++kk) {
        const float* __restrict__ wrow = W2 + kk * OUTC;
#pragma unroll
        for (int o = 0; o < OUTC; ++o)
            acc[o] = fmaf(xr[kk], wrow[o], acc[o]);
    }
#pragma unroll
    for (int j = 0; j < 4; ++j)
        *(float4*)(h2 + (long long)node * OUTC + j * 4) =
            make_float4(acc[j * 4], acc[j * 4 + 1], acc[j * 4 + 2], acc[j * 4 + 3]);
}

// ---------------- layer-2 edge aggregation (atomic scatter into d_out) -----
#define CH2 2048
__global__ __launch_bounds__(256) void k_agg2(const int* __restrict__ ei, long long E,
                                              const int* __restrict__ flag,
                                              const float* __restrict__ dinv,
                                              const float* __restrict__ h2,
                                              float* __restrict__ out) {
    int is64 = *flag;
    int lane = threadIdx.x & 63;
    int wv = threadIdx.x >> 6;
    int ch = lane & 15;
    int quart = lane >> 4;
    long long base = (long long)blockIdx.x * CH2;
    long long end = base + CH2; if (end > E) end = E;
    for (long long e = base + wv * 4 + quart; e < end; e += 16) {
        int s = edge_at(ei, e, is64);
        int d = edge_at(ei, E + e, is64);
        float nrm = dinv[s] * dinv[d];
        float v = h2[(long long)s * OUTC + ch] * nrm;
        atomicAdd(&out[(long long)d * OUTC + ch], v);
    }
}

// fin2: out += h2*dinv^2 + b2
__global__ void k_fin2(float* __restrict__ out, const float* __restrict__ h2,
                       const float* __restrict__ dinv, const float* __restrict__ b2, int n) {
    long long i = (long long)blockIdx.x * blockDim.x + threadIdx.x;
    if (i >= (long long)n * OUTC) return;
    int node = (int)(i >> 4), c = (int)(i & 15);
    float di = dinv[node];
    out[i] = out[i] + h2[i] * di * di + b2[c];
}

extern "C" void kernel_launch(void* const* d_in, const int* in_sizes, int n_in,
                              void* d_out, int out_size, void* d_ws, size_t ws_size,
                              hipStream_t stream) {
    const float* x  = (const float*)d_in[0];
    const int*   ei = (const int*)d_in[1];
    const float* W1 = (const float*)d_in[2];
    const float* b1 = (const float*)d_in[3];
    const float* W2 = (const float*)d_in[4];
    const float* b2 = (const float*)d_in[5];
    const int n = in_sizes[0] / IN_C;            // 100000
    const long long E = in_sizes[1] / 2;         // 3200000
    float* out = (float*)d_out;

    char* ws = (char*)d_ws;
    size_t off = 0;
    int*   flag = (int*)(ws + off);   off += 256;
    float* dinv = (float*)(ws + off); off += (((size_t)n * 4) + 255) & ~(size_t)255;
    float* agg1 = (float*)(ws + off); off += (((size_t)n * HIDC * 4) + 255) & ~(size_t)255;
    float* h1   = (float*)(ws + off); off += (((size_t)n * HIDC * 4) + 255) & ~(size_t)255;
    float* h2   = (float*)(ws + off); off += (((size_t)n * OUTC * 4) + 255) & ~(size_t)255;

    // zero accumulators (harness poisons d_out/d_ws with 0xAA)
    hipMemsetAsync(dinv, 0, (size_t)n * 4, stream);
    hipMemsetAsync(agg1, 0, (size_t)n * HIDC * 4, stream);
    hipMemsetAsync(out, 0, (size_t)n * OUTC * 4, stream);

    k_detect<<<1, 256, 0, stream>>>(ei, flag);
    k_deg<<<1024, 256, 0, stream>>>(ei, E, flag, dinv);
    k_dinv<<<(n + 255) / 256, 256, 0, stream>>>(dinv, n);
    k_gemm1<<<(n + 255) / 256, 256, 0, stream>>>(x, W1, h1, n);
    k_agg1<<<(int)((E + CH1 - 1) / CH1), 256, 0, stream>>>(ei, E, flag, dinv, h1, agg1);
    k_fin1<<<(int)(((long long)n * HIDC + 255) / 256), 256, 0, stream>>>(h1, agg1, dinv, b1, n);
    k_gemm2<<<(n + 255) / 256, 256, 0, stream>>>(h1, W2, h2, n);
    k_agg2<<<(int)((E + CH2 - 1) / CH2), 256, 0, stream>>>(ei, E, flag, dinv, h2, out);
    k_fin2<<<(int)(((long long)n * OUTC + 255) / 256), 256, 0, stream>>>(out, h2, dinv, b2, n);
}

// Round 2
// 516.040 us; speedup vs baseline: 1.4994x; 1.4994x over previous
//
#include <hip/hip_runtime.h>

#define IN_C 256
#define HIDC 32
#define OUTC 16

// ---------------- edge index loader (handles int32 or int64 storage) -------
__device__ __forceinline__ int edge_at(const int* __restrict__ ei, long long idx, int is64) {
    return is64 ? ei[idx << 1] : ei[idx];
}

// Detect int64 vs int32 storage: sample odd 32-bit words; all-zero => int64.
__global__ void k_detect(const int* __restrict__ ei, int* __restrict__ flag) {
    __shared__ int nz;
    if (threadIdx.x == 0) nz = 0;
    __syncthreads();
    if (ei[2 * threadIdx.x + 1] != 0) atomicOr(&nz, 1);
    __syncthreads();
    if (threadIdx.x == 0) *flag = (nz == 0) ? 1 : 0;
}

// ---------------- CSR build --------------------------------------------------
// count: int histogram over dst
__global__ void k_count(const int* __restrict__ ei, long long E,
                        const int* __restrict__ flag, int* __restrict__ cnt) {
    int is64 = *flag;
    long long stride = (long long)gridDim.x * blockDim.x;
    for (long long i = (long long)blockIdx.x * blockDim.x + threadIdx.x; i < E; i += stride)
        atomicAdd(&cnt[edge_at(ei, E + i, is64)], 1);
}

// dinv = rsqrt(cnt + 1)   (+1 = self-loop)
__global__ void k_dinv(const int* __restrict__ cnt, float* __restrict__ dinv, int n) {
    int i = blockIdx.x * blockDim.x + threadIdx.x;
    if (i < n) dinv[i] = rsqrtf((float)cnt[i] + 1.0f);
}

// scan1: per-block (256 elems) local exclusive scan into ptr, block total into bsum
__global__ __launch_bounds__(256) void k_scan1(const int* __restrict__ cnt,
                                               int* __restrict__ ptr,
                                               int* __restrict__ bsum, int n) {
    __shared__ int sm[256];
    int t = threadIdx.x;
    int i = blockIdx.x * 256 + t;
    int v = (i < n) ? cnt[i] : 0;
    sm[t] = v;
    __syncthreads();
    for (int o = 1; o < 256; o <<= 1) {
        int x = (t >= o) ? sm[t - o] : 0;
        __syncthreads();
        sm[t] += x;
        __syncthreads();
    }
    if (i < n) ptr[i] = sm[t] - v;           // local exclusive
    if (t == 255) bsum[blockIdx.x] = sm[255];
}

// scan2: single-block exclusive scan of block sums (nb <= 512)
__global__ __launch_bounds__(512) void k_scan2(int* __restrict__ bsum, int nb) {
    __shared__ int sm[512];
    int t = threadIdx.x;
    int v = (t < nb) ? bsum[t] : 0;
    sm[t] = v;
    __syncthreads();
    for (int o = 1; o < 512; o <<= 1) {
        int x = (t >= o) ? sm[t - o] : 0;
        __syncthreads();
        sm[t] += x;
        __syncthreads();
    }
    if (t < nb) bsum[t] = sm[t] - v;         // exclusive
}

// scan3: add block offsets
__global__ void k_scan3(int* __restrict__ ptr, const int* __restrict__ bsum, int n) {
    int i = blockIdx.x * blockDim.x + threadIdx.x;
    if (i < n) ptr[i] += bsum[blockIdx.x * 256 / 256 == 0 ? 0 : 0];  // placeholder (see below)
}

// (real scan3 — keep the indexing trivial and correct)
__global__ void k_scan3b(int* __restrict__ ptr, const int* __restrict__ bsum, int n) {
    int i = blockIdx.x * 256 + threadIdx.x;
    if (i < n) ptr[i] += bsum[blockIdx.x];
}

// scatter: csr_src[ptr[dst] + rank] = src
__global__ void k_scatter(const int* __restrict__ ei, long long E,
                          const int* __restrict__ flag,
                          const int* __restrict__ ptr,
                          int* __restrict__ cursor, int* __restrict__ csr_src) {
    int is64 = *flag;
    long long stride = (long long)gridDim.x * blockDim.x;
    for (long long i = (long long)blockIdx.x * blockDim.x + threadIdx.x; i < E; i += stride) {
        int s = edge_at(ei, i, is64);
        int d = edge_at(ei, E + i, is64);
        int r = atomicAdd(&cursor[d], 1);
        csr_src[ptr[d] + r] = s;
    }
}

// ---------------- gemm1: h1 = x @ W1  [n,256]x[256,32] ---------------------
#define G1_KC 32
__global__ __launch_bounds__(256) void k_gemm1(const float* __restrict__ x,
                                               const float* __restrict__ W1,
                                               float* __restrict__ h1, int n) {
    __shared__ float xs[256][40];
    const int t = threadIdx.x;
    const int node = blockIdx.x * 256 + t;
    float acc[HIDC];
#pragma unroll
    for (int o = 0; o < HIDC; ++o) acc[o] = 0.f;

    for (int k0 = 0; k0 < IN_C; k0 += G1_KC) {
#pragma unroll
        for (int it = 0; it < 8; ++it) {
            int i = it * 256 + t;
            int row = i >> 3;
            int c4 = i & 7;
            int gnode = blockIdx.x * 256 + row;
            float4 v = make_float4(0.f, 0.f, 0.f, 0.f);
            if (gnode < n)
                v = *(const float4*)(x + (long long)gnode * IN_C + k0 + c4 * 4);
            *(float4*)&xs[row][c4 * 4] = v;
        }
        __syncthreads();
        float xr[G1_KC];
#pragma unroll
        for (int j = 0; j < 8; ++j) {
            float4 v = *(const float4*)&xs[t][j * 4];
            xr[j * 4 + 0] = v.x; xr[j * 4 + 1] = v.y;
            xr[j * 4 + 2] = v.z; xr[j * 4 + 3] = v.w;
        }
#pragma unroll
        for (int kk = 0; kk < G1_KC; ++kk) {
            const float* __restrict__ wrow = W1 + (long long)(k0 + kk) * HIDC;
#pragma unroll
            for (int o = 0; o < HIDC; ++o)
                acc[o] = fmaf(xr[kk], wrow[o], acc[o]);
        }
        __syncthreads();
    }
    if (node < n) {
#pragma unroll
        for (int j = 0; j < 8; ++j)
            *(float4*)(h1 + (long long)node * HIDC + j * 4) =
                make_float4(acc[j * 4], acc[j * 4 + 1], acc[j * 4 + 2], acc[j * 4 + 3]);
    }
}

// ---------------- layer-1 pull aggregation + fused finalize ----------------
// half-wave (32 lanes = 32 channels) per dst node; register accumulate,
// one 128B write; h1r = relu((h1[dst]*di + sum(h1[s]*dinv[s])) * di + b1)
__global__ __launch_bounds__(256) void k_agg1csr(const int* __restrict__ ptr,
                                                 const int* __restrict__ cnt,
                                                 const int* __restrict__ csr_src,
                                                 const float* __restrict__ dinv,
                                                 const float* __restrict__ h1,
                                                 const float* __restrict__ b1,
                                                 float* __restrict__ h1r, int n) {
    long long g = (long long)blockIdx.x * blockDim.x + threadIdx.x;
    int node = (int)(g >> 5);
    int ch = (int)(g & 31);
    if (node >= n) return;
    float di = dinv[node];
    float acc = h1[(long long)node * HIDC + ch] * di;   // self-loop (one di now, one later)
    int st = ptr[node], deg = cnt[node];
    int j = 0;
    for (; j + 3 < deg; j += 4) {
        int s0 = csr_src[st + j], s1 = csr_src[st + j + 1];
        int s2 = csr_src[st + j + 2], s3 = csr_src[st + j + 3];
        float a0 = h1[(long long)s0 * HIDC + ch] * dinv[s0];
        float a1 = h1[(long long)s1 * HIDC + ch] * dinv[s1];
        float a2 = h1[(long long)s2 * HIDC + ch] * dinv[s2];
        float a3 = h1[(long long)s3 * HIDC + ch] * dinv[s3];
        acc += (a0 + a1) + (a2 + a3);
    }
    for (; j < deg; ++j) {
        int s = csr_src[st + j];
        acc += h1[(long long)s * HIDC + ch] * dinv[s];
    }
    float v = acc * di + b1[ch];
    h1r[(long long)node * HIDC + ch] = v > 0.f ? v : 0.f;
}

// ---------------- gemm2: h2 = h1r @ W2  [n,32]x[32,16] ---------------------
__global__ __launch_bounds__(256) void k_gemm2(const float* __restrict__ h1,
                                               const float* __restrict__ W2,
                                               float* __restrict__ h2, int n) {
    int node = blockIdx.x * 256 + threadIdx.x;
    if (node >= n) return;
    float xr[HIDC];
#pragma unroll
    for (int j = 0; j < 8; ++j) {
        float4 v = *(const float4*)(h1 + (long long)node * HIDC + j * 4);
        xr[j * 4 + 0] = v.x; xr[j * 4 + 1] = v.y;
        xr[j * 4 + 2] = v.z; xr[j * 4 + 3] = v.w;
    }
    float acc[OUTC];
#pragma unroll
    for (int o = 0; o < OUTC; ++o) acc[o] = 0.f;
#pragma unroll
    for (int kk = 0; kk < HIDC; ++kk) {
        const float* __restrict__ wrow = W2 + kk * OUTC;
#pragma unroll
        for (int o = 0; o < OUTC; ++o)
            acc[o] = fmaf(xr[kk], wrow[o], acc[o]);
    }
#pragma unroll
    for (int j = 0; j < 4; ++j)
        *(float4*)(h2 + (long long)node * OUTC + j * 4) =
            make_float4(acc[j * 4], acc[j * 4 + 1], acc[j * 4 + 2], acc[j * 4 + 3]);
}

// ---------------- layer-2 pull aggregation + fused finalize ----------------
// quarter-wave (16 lanes = 16 channels) per dst node; writes d_out directly.
__global__ __launch_bounds__(256) void k_agg2csr(const int* __restrict__ ptr,
                                                 const int* __restrict__ cnt,
                                                 const int* __restrict__ csr_src,
                                                 const float* __restrict__ dinv,
                                                 const float* __restrict__ h2,
                                                 const float* __restrict__ b2,
                                                 float* __restrict__ out, int n) {
    long long g = (long long)blockIdx.x * blockDim.x + threadIdx.x;
    int node = (int)(g >> 4);
    int ch = (int)(g & 15);
    if (node >= n) return;
    float di = dinv[node];
    float acc = h2[(long long)node * OUTC + ch] * di;
    int st = ptr[node], deg = cnt[node];
    int j = 0;
    for (; j + 3 < deg; j += 4) {
        int s0 = csr_src[st + j], s1 = csr_src[st + j + 1];
        int s2 = csr_src[st + j + 2], s3 = csr_src[st + j + 3];
        float a0 = h2[(long long)s0 * OUTC + ch] * dinv[s0];
        float a1 = h2[(long long)s1 * OUTC + ch] * dinv[s1];
        float a2 = h2[(long long)s2 * OUTC + ch] * dinv[s2];
        float a3 = h2[(long long)s3 * OUTC + ch] * dinv[s3];
        acc += (a0 + a1) + (a2 + a3);
    }
    for (; j < deg; ++j) {
        int s = csr_src[st + j];
        acc += h2[(long long)s * OUTC + ch] * dinv[s];
    }
    out[(long long)node * OUTC + ch] = acc * di + b2[ch];
}

extern "C" void kernel_launch(void* const* d_in, const int* in_sizes, int n_in,
                              void* d_out, int out_size, void* d_ws, size_t ws_size,
                              hipStream_t stream) {
    const float* x  = (const float*)d_in[0];
    const int*   ei = (const int*)d_in[1];
    const float* W1 = (const float*)d_in[2];
    const float* b1 = (const float*)d_in[3];
    const float* W2 = (const float*)d_in[4];
    const float* b2 = (const float*)d_in[5];
    const int n = in_sizes[0] / IN_C;            // 100000
    const long long E = in_sizes[1] / 2;         // 3200000
    float* out = (float*)d_out;

    char* ws = (char*)d_ws;
    size_t off = 0;
    auto alloc = [&](size_t bytes) { void* p = ws + off; off += (bytes + 255) & ~(size_t)255; return p; };
    int*   flag    = (int*)alloc(256);
    float* dinv    = (float*)alloc((size_t)n * 4);
    int*   cnt     = (int*)alloc((size_t)n * 4);
    int*   ptr     = (int*)alloc((size_t)n * 4);
    int*   cursor  = (int*)alloc((size_t)n * 4);
    int*   bsum    = (int*)alloc(512 * 4);
    int*   csr_src = (int*)alloc((size_t)E * 4);
    float* h1      = (float*)alloc((size_t)n * HIDC * 4);
    float* h1r     = (float*)alloc((size_t)n * HIDC * 4);
    float* h2      = h1;  // h1 (pre-relu) is dead after k_agg1csr; reuse its space

    hipMemsetAsync(cnt, 0, (size_t)n * 4, stream);
    hipMemsetAsync(cursor, 0, (size_t)n * 4, stream);

    const int nb = (n + 255) / 256;  // 391 <= 512

    k_detect<<<1, 256, 0, stream>>>(ei, flag);
    k_count<<<1024, 256, 0, stream>>>(ei, E, flag, cnt);
    k_dinv<<<nb, 256, 0, stream>>>(cnt, dinv, n);
    k_scan1<<<nb, 256, 0, stream>>>(cnt, ptr, bsum, n);
    k_scan2<<<1, 512, 0, stream>>>(bsum, nb);
    k_scan3b<<<nb, 256, 0, stream>>>(ptr, bsum, n);
    k_scatter<<<1024, 256, 0, stream>>>(ei, E, flag, ptr, cursor, csr_src);

    k_gemm1<<<nb, 256, 0, stream>>>(x, W1, h1, n);
    k_agg1csr<<<(int)(((long long)n * HIDC + 255) / 256), 256, 0, stream>>>(
        ptr, cnt, csr_src, dinv, h1, b1, h1r, n);
    k_gemm2<<<nb, 256, 0, stream>>>(h1r, W2, h2, n);
    k_agg2csr<<<(int)(((long long)n * OUTC + 255) / 256), 256, 0, stream>>>(
        ptr, cnt, csr_src, dinv, h2, b2, out, n);
}